// Round 5
// baseline (360.484 us; speedup 1.0000x reference)
//
#include <hip/hip_runtime.h>

// ImageWiseConv2d: per-sample conv, images [64,64,128,128] f32, kernels [64,64,3,3] f32
// out [64,1,126,126] f32 (VALID, stride 1).
//
// R8: LDS-staged version (T3/T4 recipe: global_load_lds + counted vmcnt + raw s_barrier).
// Evidence: R3/R6/R7 (register-level variants spanning -50% requests, -33% bytes,
// 4x prefetch depth) all land at 354.9-356.7 us total -> VMEM-side register tweaks
// exhausted. R5 (+50% traffic) +36us. Two live hypotheses:
//   H1: kernel ~96us, bound by per-thread L1-path latency serialization -> LDS DMA
//       staging removes it -> total ~305-325.
//   H2: kernel already ~36-46us at HBM roofline; ~310us is harness fills (profile shows
//       1 GiB fillBufferAligned @ ~160us each) -> total stays ~352-360 -> declare.
// Structure: block = 16 output rows x full width (as before). Per channel, stage the
// 18-row x 512B input window (9216 B, contiguous) into LDS via 3 global_load_lds
// (dwordx4) per wave (uniform count -> s_waitcnt vmcnt(3) in steady state, vmcnt(0)
// only on the last channel). Double-buffered; raw s_barrier (no compiler vmcnt(0)
// drain). Compute phase: 4x ds_read_b128 + shuffle halo + 72 FMA per thread per
// channel (identical math/order to R6 -> same numerics).
// LDS: 2 x 9216 B = 18.4 KB. VGPR ~50. launch_bounds(256,2).

#define NS    64
#define CCH   64
#define HH    128
#define WW    128
#define OHH   126
#define OWW   126
#define CHS   (HH * WW)      // 16384 floats per channel
#define WROWS 18             // staged input rows per block window
#define WFLT  (WROWS * WW)   // 2304 floats = 9216 B

// Stage one channel's 18-row window into LDS buffer `dbuf` (float*, shared).
// 3 global_load_lds per wave: rounds 0,1 full (64 lanes x 16B), round 2 lanes 0..15.
// Dest base is wave-uniform; HW adds lane*16. Source is per-lane (contiguous).
#define STAGE_CH(dbuf, cc)                                                          \
    {                                                                               \
        const float* chb_ = imgn + (cc) * CHS;                                      \
        {   /* round 0: elements 0..255, rows 0..7 */                               \
            const int e_ = wid * 64 + lane;                                         \
            const float* s_ = chb_ + (h0 + (e_ >> 5)) * WW + (e_ & 31) * 4;         \
            __builtin_amdgcn_global_load_lds(                                       \
                (const __attribute__((address_space(1))) void*)s_,                  \
                (__attribute__((address_space(3))) void*)&(dbuf)[(wid * 64) * 4],   \
                16, 0, 0);                                                          \
        }                                                                           \
        {   /* round 1: elements 256..511, rows 8..15 */                            \
            const int e_ = 256 + wid * 64 + lane;                                   \
            const float* s_ = chb_ + (h0 + (e_ >> 5)) * WW + (e_ & 31) * 4;         \
            __builtin_amdgcn_global_load_lds(                                       \
                (const __attribute__((address_space(1))) void*)s_,                  \
                (__attribute__((address_space(3))) void*)&(dbuf)[(256 + wid * 64) * 4], \
                16, 0, 0);                                                          \
        }                                                                           \
        if (lane < 16) { /* round 2: elements 512..575, rows 16..17 (clamp bt=7) */ \
            const int e_ = 512 + wid * 16 + lane;                                   \
            int srow_ = h0 + (e_ >> 5);                                             \
            if (srow_ > HH - 1) srow_ = HH - 1;                                     \
            const float* s_ = chb_ + srow_ * WW + (e_ & 31) * 4;                    \
            __builtin_amdgcn_global_load_lds(                                       \
                (const __attribute__((address_space(1))) void*)s_,                  \
                (__attribute__((address_space(3))) void*)&(dbuf)[(512 + wid * 16) * 4], \
                16, 0, 0);                                                          \
        }                                                                           \
    }

__global__ __launch_bounds__(256, 2)
void ImageWiseConv2d_lds(const float* __restrict__ img,
                         const float* __restrict__ ker,
                         float* __restrict__ out)
{
    __shared__ float buf[2][WFLT];       // 2 x 9216 B, double buffer

    const int tid  = threadIdx.x;
    const int lane = tid & 63;
    const int wid  = tid >> 6;           // wave id 0..3
    const int bx   = blockIdx.x;         // 0..511
    const int bt   = bx & 7;             // row tile (16 output rows)
    const int n    = bx >> 3;            // sample
    const int h0   = bt * 16;

    const int r0 = (tid >> 5) << 1;      // patch top output row within tile: 0..14
    const int c0 = (tid & 31) << 2;      // patch left output col: 0..124

    const float* imgn = img + (size_t)(n * CCH) * CHS;
    const float* kp   = ker + n * CCH * 9;   // block-uniform -> scalar loads

    float a00 = 0.f, a01 = 0.f, a02 = 0.f, a03 = 0.f;
    float a10 = 0.f, a11 = 0.f, a12 = 0.f, a13 = 0.f;

    // prologue: stage channel 0 into buf[0]
    STAGE_CH(buf[0], 0);

    for (int c = 0; c < CCH; ++c) {
        if (c + 1 < CCH) {
            // issue async stage of next channel, then wait for CURRENT channel's
            // 3 loads (leaving the 3 just-issued in flight) and rendezvous.
            STAGE_CH(buf[(c + 1) & 1], c + 1);
            asm volatile("s_waitcnt vmcnt(3)\n\ts_barrier" ::: "memory");
        } else {
            asm volatile("s_waitcnt vmcnt(0)\n\ts_barrier" ::: "memory");
        }

        // ---- compute channel c from buf[c&1] ----
        const float* cb = &buf[c & 1][r0 * WW + c0];
        const float4 A0 = *(const float4*)(cb);
        const float4 A1 = *(const float4*)(cb + WW);
        const float4 A2 = *(const float4*)(cb + 2 * WW);
        const float4 A3 = *(const float4*)(cb + 3 * WW);

        const float w0 = kp[c * 9 + 0], w1 = kp[c * 9 + 1], w2 = kp[c * 9 + 2];
        const float w3 = kp[c * 9 + 3], w4 = kp[c * 9 + 4], w5 = kp[c * 9 + 5];
        const float w6 = kp[c * 9 + 6], w7 = kp[c * 9 + 7], w8 = kp[c * 9 + 8];

        // halo cols c0+4,c0+5 live in lane+1's A.x,A.y. Garbage only where c0=124
        // (lanes 31/63), whose a*2/a*3 are never stored.
        const float h40 = __shfl_down(A0.x, 1), h50 = __shfl_down(A0.y, 1);
        const float h41 = __shfl_down(A1.x, 1), h51 = __shfl_down(A1.y, 1);
        const float h42 = __shfl_down(A2.x, 1), h52 = __shfl_down(A2.y, 1);
        const float h43 = __shfl_down(A3.x, 1), h53 = __shfl_down(A3.y, 1);

        {   // row 0 -> acc0 (kernel row 0)
            const float v0 = A0.x, v1 = A0.y, v2 = A0.z, v3 = A0.w, v4 = h40, v5 = h50;
            a00 = fmaf(w0, v0, a00); a00 = fmaf(w1, v1, a00); a00 = fmaf(w2, v2, a00);
            a01 = fmaf(w0, v1, a01); a01 = fmaf(w1, v2, a01); a01 = fmaf(w2, v3, a01);
            a02 = fmaf(w0, v2, a02); a02 = fmaf(w1, v3, a02); a02 = fmaf(w2, v4, a02);
            a03 = fmaf(w0, v3, a03); a03 = fmaf(w1, v4, a03); a03 = fmaf(w2, v5, a03);
        }
        {   // row 1 -> acc0 (kr 1), acc1 (kr 0)
            const float v0 = A1.x, v1 = A1.y, v2 = A1.z, v3 = A1.w, v4 = h41, v5 = h51;
            a00 = fmaf(w3, v0, a00); a00 = fmaf(w4, v1, a00); a00 = fmaf(w5, v2, a00);
            a01 = fmaf(w3, v1, a01); a01 = fmaf(w4, v2, a01); a01 = fmaf(w5, v3, a01);
            a02 = fmaf(w3, v2, a02); a02 = fmaf(w4, v3, a02); a02 = fmaf(w5, v4, a02);
            a03 = fmaf(w3, v3, a03); a03 = fmaf(w4, v4, a03); a03 = fmaf(w5, v5, a03);
            a10 = fmaf(w0, v0, a10); a10 = fmaf(w1, v1, a10); a10 = fmaf(w2, v2, a10);
            a11 = fmaf(w0, v1, a11); a11 = fmaf(w1, v2, a11); a11 = fmaf(w2, v3, a11);
            a12 = fmaf(w0, v2, a12); a12 = fmaf(w1, v3, a12); a12 = fmaf(w2, v4, a12);
            a13 = fmaf(w0, v3, a13); a13 = fmaf(w1, v4, a13); a13 = fmaf(w2, v5, a13);
        }
        {   // row 2 -> acc0 (kr 2), acc1 (kr 1)
            const float v0 = A2.x, v1 = A2.y, v2 = A2.z, v3 = A2.w, v4 = h42, v5 = h52;
            a00 = fmaf(w6, v0, a00); a00 = fmaf(w7, v1, a00); a00 = fmaf(w8, v2, a00);
            a01 = fmaf(w6, v1, a01); a01 = fmaf(w7, v2, a01); a01 = fmaf(w8, v3, a01);
            a02 = fmaf(w6, v2, a02); a02 = fmaf(w7, v3, a02); a02 = fmaf(w8, v4, a02);
            a03 = fmaf(w6, v3, a03); a03 = fmaf(w7, v4, a03); a03 = fmaf(w8, v5, a03);
            a10 = fmaf(w3, v0, a10); a10 = fmaf(w4, v1, a10); a10 = fmaf(w5, v2, a10);
            a11 = fmaf(w3, v1, a11); a11 = fmaf(w4, v2, a11); a11 = fmaf(w5, v3, a11);
            a12 = fmaf(w3, v2, a12); a12 = fmaf(w4, v3, a12); a12 = fmaf(w5, v4, a12);
            a13 = fmaf(w3, v3, a13); a13 = fmaf(w4, v4, a13); a13 = fmaf(w5, v5, a13);
        }
        {   // row 3 -> acc1 (kr 2)
            const float v0 = A3.x, v1 = A3.y, v2 = A3.z, v3 = A3.w, v4 = h43, v5 = h53;
            a10 = fmaf(w6, v0, a10); a10 = fmaf(w7, v1, a10); a10 = fmaf(w8, v2, a10);
            a11 = fmaf(w6, v1, a11); a11 = fmaf(w7, v2, a11); a11 = fmaf(w8, v3, a11);
            a12 = fmaf(w6, v2, a12); a12 = fmaf(w7, v3, a12); a12 = fmaf(w8, v4, a12);
            a13 = fmaf(w6, v3, a13); a13 = fmaf(w7, v4, a13); a13 = fmaf(w8, v5, a13);
        }

        // all waves done reading buf[c&1] before it gets re-staged next iteration
        asm volatile("s_barrier" ::: "memory");
    }

    // ---- store 2x4 (float2 pairs: out rows are 8B- but not 16B-aligned) ----
    const int oh0 = h0 + r0;
    if (oh0 < OHH) {           // oh0 invalid only for bt=7,r0=14, where oh0+1 is too
        float* o0 = out + (n * OHH + oh0) * OWW + c0;
        float* o1 = o0 + OWW;
        *(float2*)o0 = make_float2(a00, a01);
        *(float2*)o1 = make_float2(a10, a11);
        if (c0 < 124) {
            *(float2*)(o0 + 2) = make_float2(a02, a03);
            *(float2*)(o1 + 2) = make_float2(a12, a13);
        }
    }
}

extern "C" void kernel_launch(void* const* d_in, const int* in_sizes, int n_in,
                              void* d_out, int out_size, void* d_ws, size_t ws_size,
                              hipStream_t stream) {
    const float* img = (const float*)d_in[0];   // [64,64,128,128] f32
    const float* ker = (const float*)d_in[1];   // [64,64,3,3] f32
    float* out = (float*)d_out;                 // [64,1,126,126] f32

    ImageWiseConv2d_lds<<<dim3(NS * 8), dim3(256), 0, stream>>>(img, ker, out);
}

// Round 6
// 354.948 us; speedup vs baseline: 1.0156x; 1.0156x over previous
//
#include <hip/hip_runtime.h>

// ImageWiseConv2d: per-sample conv, images [64,64,128,128] f32, kernels [64,64,3,3] f32
// out [64,1,126,126] f32 (VALID, stride 1).
//
// R9: REVERT to R6, the best measured variant (354.9 us total) — final polish round.
// Session evidence (5 structural variants): R3 356.7 / R5 392.9 / R6 354.9 / R7 356.0 /
// R8 (LDS+DMA+counted vmcnt) 360.5. Attacked bytes (-33%), requests (-50%), TLP (2x),
// prefetch depth (4x), and the L1 path (LDS staging) -- all neutral-to-negative.
// Model: kernel is at its compulsory-HBM floor (~260 MB unique -> ~45 us at the
// fill-calibrated 6.6 TB/s ceiling); the ~310 us residual is harness fill/overhead
// (1-GiB fillBufferAligned dispatches at 83% HBM peak dominate the timed region).
// R8's +5.6 us = 64 iters of barrier/vmcnt rendezvous on top of the floor -- confirms
// barrier-free streaming is the right endpoint. This kernel: 2x4 out/thread, 4x float4
// loads/channel, halo via __shfl_down (DS pipe), 1-deep reg prefetch, no LDS, no
// barriers, weights via wave-uniform scalar loads. launch_bounds(256,2): no spill.

#define NS   64
#define CCH  64
#define HH   128
#define WW   128
#define OHH  126
#define OWW  126
#define CHS  (HH * WW)   // 16384 floats per channel

__global__ __launch_bounds__(256, 2)
void ImageWiseConv2d_direct(const float* __restrict__ img,
                            const float* __restrict__ ker,
                            float* __restrict__ out)
{
    const int tid = threadIdx.x;
    const int bx  = blockIdx.x;          // 0..511
    const int bt  = bx & 7;              // row tile (16 output rows)
    const int n   = bx >> 3;             // sample
    const int h0  = bt * 16;

    const int r0 = (tid >> 5) << 1;      // patch top output row within tile: 0..14
    const int c0 = (tid & 31) << 2;      // patch left output col: 0..124

    // input rows ihr..ihr+3; clamp so we never read past row 127 (clamped case is
    // bt=7,r0=14 whose outputs are discarded)
    int ihr = h0 + r0;
    if (ihr > HH - 4) ihr = HH - 4;

    const float* p0 = img + (((n * CCH) * HH) + ihr) * WW + c0;
    const float* kp = ker + (n * CCH) * 9;   // block-uniform -> scalar loads

    float a00 = 0.f, a01 = 0.f, a02 = 0.f, a03 = 0.f;
    float a10 = 0.f, a11 = 0.f, a12 = 0.f, a13 = 0.f;

    // current-channel patch registers: 4 rows x float4 (halo via shfl)
    float4 A0, A1, A2, A3;
    A0 = *(const float4*)(p0);
    A1 = *(const float4*)(p0 + WW);
    A2 = *(const float4*)(p0 + 2 * WW);
    A3 = *(const float4*)(p0 + 3 * WW);

    for (int c = 0; c < CCH; ++c) {
        // prefetch next channel into fresh registers (no barrier anywhere)
        float4 nA0, nA1, nA2, nA3;
        const bool more = (c + 1 < CCH);
        if (more) {
            const float* q = p0 + (c + 1) * CHS;
            nA0 = *(const float4*)(q);
            nA1 = *(const float4*)(q + WW);
            nA2 = *(const float4*)(q + 2 * WW);
            nA3 = *(const float4*)(q + 3 * WW);
        }

        const float w0 = kp[c * 9 + 0], w1 = kp[c * 9 + 1], w2 = kp[c * 9 + 2];
        const float w3 = kp[c * 9 + 3], w4 = kp[c * 9 + 4], w5 = kp[c * 9 + 5];
        const float w6 = kp[c * 9 + 6], w7 = kp[c * 9 + 7], w8 = kp[c * 9 + 8];

        // halo values: cols c0+4, c0+5 live in lane+1's A.x, A.y.
        // Garbage for lane 31 within each row-group (crosses into other row / wave end),
        // but those lanes have c0=124 where only a*0/a*1 are stored.
        const float h40 = __shfl_down(A0.x, 1), h50 = __shfl_down(A0.y, 1);
        const float h41 = __shfl_down(A1.x, 1), h51 = __shfl_down(A1.y, 1);
        const float h42 = __shfl_down(A2.x, 1), h52 = __shfl_down(A2.y, 1);
        const float h43 = __shfl_down(A3.x, 1), h53 = __shfl_down(A3.y, 1);

        // row 0 -> acc0 (kernel row 0)
        {
            const float v0 = A0.x, v1 = A0.y, v2 = A0.z, v3 = A0.w, v4 = h40, v5 = h50;
            a00 = fmaf(w0, v0, a00); a00 = fmaf(w1, v1, a00); a00 = fmaf(w2, v2, a00);
            a01 = fmaf(w0, v1, a01); a01 = fmaf(w1, v2, a01); a01 = fmaf(w2, v3, a01);
            a02 = fmaf(w0, v2, a02); a02 = fmaf(w1, v3, a02); a02 = fmaf(w2, v4, a02);
            a03 = fmaf(w0, v3, a03); a03 = fmaf(w1, v4, a03); a03 = fmaf(w2, v5, a03);
        }
        // row 1 -> acc0 (kr 1), acc1 (kr 0)
        {
            const float v0 = A1.x, v1 = A1.y, v2 = A1.z, v3 = A1.w, v4 = h41, v5 = h51;
            a00 = fmaf(w3, v0, a00); a00 = fmaf(w4, v1, a00); a00 = fmaf(w5, v2, a00);
            a01 = fmaf(w3, v1, a01); a01 = fmaf(w4, v2, a01); a01 = fmaf(w5, v3, a01);
            a02 = fmaf(w3, v2, a02); a02 = fmaf(w4, v3, a02); a02 = fmaf(w5, v4, a02);
            a03 = fmaf(w3, v3, a03); a03 = fmaf(w4, v4, a03); a03 = fmaf(w5, v5, a03);
            a10 = fmaf(w0, v0, a10); a10 = fmaf(w1, v1, a10); a10 = fmaf(w2, v2, a10);
            a11 = fmaf(w0, v1, a11); a11 = fmaf(w1, v2, a11); a11 = fmaf(w2, v3, a11);
            a12 = fmaf(w0, v2, a12); a12 = fmaf(w1, v3, a12); a12 = fmaf(w2, v4, a12);
            a13 = fmaf(w0, v3, a13); a13 = fmaf(w1, v4, a13); a13 = fmaf(w2, v5, a13);
        }
        // row 2 -> acc0 (kr 2), acc1 (kr 1)
        {
            const float v0 = A2.x, v1 = A2.y, v2 = A2.z, v3 = A2.w, v4 = h42, v5 = h52;
            a00 = fmaf(w6, v0, a00); a00 = fmaf(w7, v1, a00); a00 = fmaf(w8, v2, a00);
            a01 = fmaf(w6, v1, a01); a01 = fmaf(w7, v2, a01); a01 = fmaf(w8, v3, a01);
            a02 = fmaf(w6, v2, a02); a02 = fmaf(w7, v3, a02); a02 = fmaf(w8, v4, a02);
            a03 = fmaf(w6, v3, a03); a03 = fmaf(w7, v4, a03); a03 = fmaf(w8, v5, a03);
            a10 = fmaf(w3, v0, a10); a10 = fmaf(w4, v1, a10); a10 = fmaf(w5, v2, a10);
            a11 = fmaf(w3, v1, a11); a11 = fmaf(w4, v2, a11); a11 = fmaf(w5, v3, a11);
            a12 = fmaf(w3, v2, a12); a12 = fmaf(w4, v3, a12); a12 = fmaf(w5, v4, a12);
            a13 = fmaf(w3, v3, a13); a13 = fmaf(w4, v4, a13); a13 = fmaf(w5, v5, a13);
        }
        // row 3 -> acc1 (kr 2)
        {
            const float v0 = A3.x, v1 = A3.y, v2 = A3.z, v3 = A3.w, v4 = h43, v5 = h53;
            a10 = fmaf(w6, v0, a10); a10 = fmaf(w7, v1, a10); a10 = fmaf(w8, v2, a10);
            a11 = fmaf(w6, v1, a11); a11 = fmaf(w7, v2, a11); a11 = fmaf(w8, v3, a11);
            a12 = fmaf(w6, v2, a12); a12 = fmaf(w7, v3, a12); a12 = fmaf(w8, v4, a12);
            a13 = fmaf(w6, v3, a13); a13 = fmaf(w7, v4, a13); a13 = fmaf(w8, v5, a13);
        }

        if (more) {
            A0 = nA0; A1 = nA1; A2 = nA2; A3 = nA3;
        }
    }

    // ---- store 2x4 (float2 pairs: out rows are 8B- but not 16B-aligned) ----
    const int oh0 = h0 + r0;
    if (oh0 < OHH) {           // oh0 invalid only for bt=7,r0=14, where oh0+1 is too
        float* o0 = out + (n * OHH + oh0) * OWW + c0;
        float* o1 = o0 + OWW;
        *(float2*)o0 = make_float2(a00, a01);
        *(float2*)o1 = make_float2(a10, a11);
        if (c0 < 124) {
            *(float2*)(o0 + 2) = make_float2(a02, a03);
            *(float2*)(o1 + 2) = make_float2(a12, a13);
        }
    }
}

extern "C" void kernel_launch(void* const* d_in, const int* in_sizes, int n_in,
                              void* d_out, int out_size, void* d_ws, size_t ws_size,
                              hipStream_t stream) {
    const float* img = (const float*)d_in[0];   // [64,64,128,128] f32
    const float* ker = (const float*)d_in[1];   // [64,64,3,3] f32
    float* out = (float*)d_out;                 // [64,1,126,126] f32

    ImageWiseConv2d_direct<<<dim3(NS * 8), dim3(256), 0, stream>>>(img, ker, out);
}